// Round 2
// baseline (860.003 us; speedup 1.0000x reference)
//
#include <hip/hip_runtime.h>
#include <hip/hip_cooperative_groups.h>

namespace cg = cooperative_groups;

#define D 512
#define T 50000
#define K 16
#define NIT 10

#define NBLK 256            // exactly 1 block per CU -> coop launch always fits
#define BTH  512
#define COLS_PER_BLOCK 196  // 256*196 = 50176 >= 50000
#define NGRP 49             // 4-col groups per block
#define PASSES 2            // 2 passes x 32 groups covers 49

#define LAMBDA1 0.3366f
#define LR      0.1f
#define SHRINK_C (LR * LAMBDA1)
#define BETA1   0.9f
#define BETA2   0.999f
#define ADAM_EPS 1e-8f

__device__ __forceinline__ float sgn(float x) {
    return (x > 0.f) ? 1.f : ((x < 0.f) ? -1.f : 0.f);
}

// One persistent cooperative kernel for the whole optimization.
// Block-local state: B in LDS (32KB); P,m,v in registers (thread = row).
// Cross-block communication is ONLY the packed argmax slot (device-scope
// atomics, one slot per iteration), so per-XCD L2 non-coherence is
// irrelevant: every block performs the update redundantly on bitwise-
// identical local state (fixed-order reductions keep all block-local
// copies identical).
__global__ __launch_bounds__(BTH, 2) void diar_all(
        const float* __restrict__ E, const float* __restrict__ Bin,
        const float* __restrict__ A, float* __restrict__ out,
        unsigned long long* __restrict__ slot) {
    __shared__ __align__(16) float Bl[D * K];      // 32 KB, current B
    __shared__ float4 psum[16][32];                // 8 KB per-slice col partials
    __shared__ float wsum[8][K];                   // per-wave |B| col partials
    __shared__ float colA[K];
    __shared__ int js_s, ks_s;

    const int tid = threadIdx.x;
    const int bid = blockIdx.x;
    cg::grid_group grid = cg::this_grid();

    // ---- init block-local state: thread tid owns row tid ----
    float pr[K], mr[K], vr[K];
    {
        const float4* src = reinterpret_cast<const float4*>(Bin + tid * K);
        float4* bl4 = reinterpret_cast<float4*>(&Bl[tid * K]);
#pragma unroll
        for (int q = 0; q < 4; ++q) {
            float4 x = src[q];
            bl4[q] = x;
            pr[4 * q + 0] = x.x; pr[4 * q + 1] = x.y;
            pr[4 * q + 2] = x.z; pr[4 * q + 3] = x.w;
        }
#pragma unroll
        for (int k = 0; k < K; ++k) { mr[k] = 0.f; vr[k] = 0.f; }
    }
    // zero the per-iteration argmax slots (ws is poisoned 0xAA)
    if (bid == 0 && tid < NIT) atomicExch(&slot[tid], 0ull);
    __syncthreads();
    grid.sync();   // slots zeroed + everyone's Bl ready

    const int c = tid & 31;          // 4-col group lane within pass
    const int s = tid >> 5;          // row slice (32 rows)

    float b1p = 1.f, b2p = 1.f;

    for (int it = 1; it <= NIT; ++it) {
        b1p *= BETA1; b2p *= BETA2;

        // ---- phase 1: residual column abs-sums, 2 passes of 32 groups ----
        unsigned long long key = 0ull;   // accumulated in lanes tid<32
#pragma unroll
        for (int p = 0; p < PASSES; ++p) {
            const int g = p * 32 + c;
            const int j0 = bid * COLS_PER_BLOCK + g * 4;
            const bool ok = (g < NGRP) && (j0 < T);   // T%4==0: all-4-or-none
            float4 acc = {0.f, 0.f, 0.f, 0.f};
            if (ok) {
                float4 a4[K];
#pragma unroll
                for (int k = 0; k < K; ++k)
                    a4[k] = *reinterpret_cast<const float4*>(A + (size_t)k * T + j0);
                const int rbase = s * 32;
                const float* Ep = E + j0;
#pragma unroll 4
                for (int ii = 0; ii < 32; ++ii) {
                    const int i = rbase + ii;
                    const float4 e = *reinterpret_cast<const float4*>(Ep + (size_t)i * T);
                    const float4* br = reinterpret_cast<const float4*>(&Bl[i * K]);
                    float bb[K];
                    *reinterpret_cast<float4*>(&bb[0])  = br[0];
                    *reinterpret_cast<float4*>(&bb[4])  = br[1];
                    *reinterpret_cast<float4*>(&bb[8])  = br[2];
                    *reinterpret_cast<float4*>(&bb[12]) = br[3];
                    float4 r = e;
#pragma unroll
                    for (int k = 0; k < K; ++k) {
                        r.x = fmaf(-bb[k], a4[k].x, r.x);
                        r.y = fmaf(-bb[k], a4[k].y, r.y);
                        r.z = fmaf(-bb[k], a4[k].z, r.z);
                        r.w = fmaf(-bb[k], a4[k].w, r.w);
                    }
                    acc.x += fabsf(r.x); acc.y += fabsf(r.y);
                    acc.z += fabsf(r.z); acc.w += fabsf(r.w);
                }
            }
            psum[s][c] = acc;
            __syncthreads();
            if (tid < 32) {
                const int gg = p * 32 + tid;
                const int jb = bid * COLS_PER_BLOCK + gg * 4;
                if (gg < NGRP && jb < T) {
                    float4 cs = psum[0][tid];
#pragma unroll
                    for (int q = 1; q < 16; ++q) {   // fixed order -> deterministic
                        float4 pq = psum[q][tid];
                        cs.x += pq.x; cs.y += pq.y; cs.z += pq.z; cs.w += pq.w;
                    }
                    float v4[4] = {cs.x, cs.y, cs.z, cs.w};
#pragma unroll
                    for (int q = 0; q < 4; ++q) {
                        unsigned long long kq =
                            (((unsigned long long)__float_as_uint(v4[q])) << 32)
                            | (unsigned int)(jb + q);
                        if (kq > key) key = kq;     // ties -> largest j
                    }
                }
            }
            __syncthreads();   // psum reused next pass
        }
        if (tid < 64) {   // wave 0: lanes >=32 hold key=0
#pragma unroll
            for (int off = 32; off > 0; off >>= 1) {
                unsigned long long o = __shfl_down(key, off, 64);
                if (o > key) key = o;
            }
            if (tid == 0) atomicMax(&slot[it - 1], key);
        }

        grid.sync();   // all blocks' argmax contributions complete

        // ---- update (every block, redundant, bitwise-deterministic) ----
        if (tid == 0) {
            unsigned long long kk = atomicMax(&slot[it - 1], 0ull);  // coherent read
            js_s = (int)(kk & 0xffffffffull);
        }
        __syncthreads();
        const int js = js_s;
        if (tid < K) colA[tid] = A[(size_t)tid * T + js];

        // B column L1 norms: wave shuffle (fixed tree) + fixed-order wave merge
        float cb[K];
        {
            const float* brow = &Bl[tid * K];
#pragma unroll
            for (int k = 0; k < K; ++k) cb[k] = fabsf(brow[k]);
#pragma unroll
            for (int off = 32; off > 0; off >>= 1) {
#pragma unroll
                for (int k = 0; k < K; ++k) cb[k] += __shfl_down(cb[k], off, 64);
            }
            if ((tid & 63) == 0) {
                const int w = tid >> 6;
#pragma unroll
                for (int k = 0; k < K; ++k) wsum[w][k] = cb[k];
            }
        }
        __syncthreads();
        if (tid == 0) {
            float best = -1.f; int kb = 0;
#pragma unroll
            for (int k = 0; k < K; ++k) {
                float t = 0.f;
                for (int w = 0; w < 8; ++w) t += wsum[w][k];   // fixed order
                if (t > best) { best = t; kb = k; }            // first-max
            }
            ks_s = kb;
        }
        __syncthreads();
        const int ks = ks_s;
        const float biasm = 1.f - b1p;
        const float biasv = 1.f - b2p;

        // residual sign for my row at column j*
        float r = E[(size_t)tid * T + js];
        const float* brow = &Bl[tid * K];
#pragma unroll
        for (int k = 0; k < K; ++k) r = fmaf(-brow[k], colA[k], r);
        const float sg = sgn(r);

        // Adam step on P (registers), then B = shrink(P) back to LDS
#pragma unroll
        for (int k = 0; k < K; ++k) {
            float g = -sg * colA[k];
            if (k == ks) g += LAMBDA1 * sgn(brow[k]);
            float p = pr[k];
            if (it >= 2) g *= sgn(p) * sgn(p - SHRINK_C);   // d shrink/dp a.e.
            float mm = BETA1 * mr[k] + (1.f - BETA1) * g;
            float vv = BETA2 * vr[k] + (1.f - BETA2) * g * g;
            mr[k] = mm; vr[k] = vv;
            p -= LR * (mm / biasm) / (sqrtf(vv / biasv) + ADAM_EPS);
            pr[k] = p;
        }
        {
            float4* bl4 = reinterpret_cast<float4*>(&Bl[tid * K]);
#pragma unroll
            for (int q = 0; q < 4; ++q) {
                float4 x;
                x.x = sgn(pr[4 * q + 0]) * fmaxf(0.f, fabsf(pr[4 * q + 0] - SHRINK_C));
                x.y = sgn(pr[4 * q + 1]) * fmaxf(0.f, fabsf(pr[4 * q + 1] - SHRINK_C));
                x.z = sgn(pr[4 * q + 2]) * fmaxf(0.f, fabsf(pr[4 * q + 2] - SHRINK_C));
                x.w = sgn(pr[4 * q + 3]) * fmaxf(0.f, fabsf(pr[4 * q + 3] - SHRINK_C));
                bl4[q] = x;
            }
        }
        __syncthreads();   // Bl updated before next iteration's phase 1
    }

    // ---- output: [shrink(P) (8192) | A (800000)] ----
    if (bid == 0) {
        float4* o4 = reinterpret_cast<float4*>(out);
        const float4* b4 = reinterpret_cast<const float4*>(Bl);
#pragma unroll
        for (int q = 0; q < 4; ++q) o4[tid * 4 + q] = b4[tid * 4 + q];
    }
    {
        float4* o4 = reinterpret_cast<float4*>(out) + (D * K) / 4;
        const float4* a4p = reinterpret_cast<const float4*>(A);
        const int n4 = (K * T) / 4;   // 200000
        for (int q = bid * BTH + tid; q < n4; q += NBLK * BTH) o4[q] = a4p[q];
    }
}

extern "C" void kernel_launch(void* const* d_in, const int* in_sizes, int n_in,
                              void* d_out, int out_size, void* d_ws, size_t ws_size,
                              hipStream_t stream) {
    const float* E   = (const float*)d_in[0];   // (D, T)
    const float* Bin = (const float*)d_in[1];   // (D, K)
    const float* A   = (const float*)d_in[2];   // (K, T)
    float* out = (float*)d_out;
    unsigned long long* slot = (unsigned long long*)d_ws;   // NIT slots

    void* args[] = { (void*)&E, (void*)&Bin, (void*)&A, (void*)&out, (void*)&slot };
    hipLaunchCooperativeKernel((void*)diar_all, dim3(NBLK), dim3(BTH),
                               args, 0, stream);
}